// Round 16
// baseline (86.845 us; speedup 1.0000x reference)
//
#include <hip/hip_runtime.h>
#include <hip/hip_bf16.h>
#include <math.h>

#define Bn   8
#define DIM  128
#define Hs   64
#define Ws   64
#define GC   16
#define Gn   8
#define CMID 32
#define NW   392
#define NWP  416

typedef __bf16 bf16x8 __attribute__((ext_vector_type(8)));
typedef float  f32x4  __attribute__((ext_vector_type(4)));
typedef _Float16 h2v  __attribute__((ext_vector_type(2)));
typedef __fp16   fp16x2 __attribute__((ext_vector_type(2)));

__device__ __forceinline__ f32x4 mfma16(bf16x8 a, bf16x8 b, f32x4 c) {
    return __builtin_amdgcn_mfma_f32_16x16x32_bf16(a, b, c, 0, 0, 0);
}
__device__ __forceinline__ __bf16 tobf(float v) {
    __hip_bfloat16 h = __float2bfloat16(v);
    return *reinterpret_cast<__bf16*>(&h);
}
__device__ __forceinline__ unsigned su16(float f) {
    __hip_bfloat16 h = __float2bfloat16(f);
    return (unsigned)*reinterpret_cast<unsigned short*>(&h);
}
__device__ __forceinline__ unsigned pk2u(float a, float b) {
    fp16x2 p = __builtin_amdgcn_cvt_pkrtz(a, b);
    return __builtin_bit_cast(unsigned, p);
}
__device__ __forceinline__ float gelu_t(float v) {
    float u = 0.7978845608f * v * fmaf(0.044715f, v * v, 1.0f);
    float t = __builtin_amdgcn_exp2f(fminf(u, 30.f) * 2.885390082f);
    return v * t * __builtin_amdgcn_rcpf(t + 1.0f);
}

// ---------------- K0: weights -> bf16 (+pw1 K-perm); x -> PADDED f16-pair image ----------------
// xpad[c8][70][72], c8=(b,g,ccp): prow=hh+3, pcol=wc+3, zero halo. pairs (c, c+8).
// k_all j layout: j = w*64 + t4*16 + gl*4 + pi*2 + sel -> c = (w*4+gl)*16 + t4*2 + pi + 8*sel
__global__ __launch_bounds__(256) void k0_cvt(const float* __restrict__ w1,
        const float* __restrict__ w2,
        const float* __restrict__ pw1, const float* __restrict__ pw2,
        const float* __restrict__ x,
        __hip_bfloat16* __restrict__ w1b, __hip_bfloat16* __restrict__ w2b,
        __hip_bfloat16* __restrict__ mw1b, __hip_bfloat16* __restrict__ mw2b,
        unsigned* __restrict__ xpad) {
    int T = blockIdx.x * 256 + threadIdx.x;   // 524288 threads
    if (T < 32768) {
        int i = T;
        if (i < CMID * DIM) w1b[i] = __float2bfloat16(w1[i]);
        if (i < NWP * CMID)
            w2b[i] = (i < NW * CMID) ? __float2bfloat16(w2[i]) : __float2bfloat16(0.f);
        {
            int f = i >> 7, j = i & 127;
            int wv = j >> 6, t4 = (j >> 4) & 3, gl = (j >> 2) & 3;
            int pi = (j >> 1) & 1, sel = j & 1;
            mw1b[i] = __float2bfloat16(pw1[f * 128 + (wv * 4 + gl) * 16 + t4 * 2 + pi + 8 * sel]);
        }
        mw2b[i] = __float2bfloat16(pw2[i]);
    }
#pragma unroll
    for (int e = 0; e < 5; ++e) {
        int idx = T + e * 524288;
        if (idx < 512 * 5040) {
            int c8 = idx / 5040;
            int rem = idx - c8 * 5040;
            int prow = rem / 72, pcol = rem - prow * 72;
            int hh = prow - 3, wc = pcol - 3;
            int bb = c8 >> 6, gg = (c8 >> 3) & 7, cc = c8 & 7;
            unsigned v = 0;
            if ((unsigned)hh < 64u && (unsigned)wc < 64u) {
                size_t src = ((size_t)(bb * DIM + gg * GC + cc)) * 4096 + hh * 64 + wc;
                v = pk2u(x[src], x[src + 8 * 4096]);
            }
            xpad[(size_t)c8 * 5040 + rem] = v;
        }
    }
}

// ---- K_ALL: 128 threads / 2 waves per 16-px tile; channel-split; 4 barriers ----
__global__ __launch_bounds__(128) void k_all(const float* __restrict__ x,
        const unsigned* __restrict__ xpad,
        const __hip_bfloat16* __restrict__ w1b, const float* __restrict__ b1v,
        const float* __restrict__ bng, const float* __restrict__ bnb,
        const float* __restrict__ bnm, const float* __restrict__ bnv,
        const __hip_bfloat16* __restrict__ w2b, const float* __restrict__ b2v,
        const float* __restrict__ lng, const float* __restrict__ lnb,
        const __hip_bfloat16* __restrict__ mw1b, const float* __restrict__ mb1,
        const __hip_bfloat16* __restrict__ mw2b, const float* __restrict__ mb2,
        float* __restrict__ out) {
    __shared__ __align__(16) char uni[18944];
    __shared__ float psA[32], psB[32];      // DEDICATED (R14 bug: lived inside wgt2 -> race)
    // phase A
    __hip_bfloat16* tsh = (__hip_bfloat16*)uni;              // [16][34]        1088 B
    h2v* xp   = (h2v*)(uni + 1088);                          // [2w][8][7][24]  10752 B
    h2v* wgt2 = (h2v*)(uni + 11840);                         // [2w][49][18]    7056 B -> 18896
    // phase B (A dead)
    __hip_bfloat16* ylds = (__hip_bfloat16*)uni;             // [16][136]       4352 B
    __hip_bfloat16* zsh  = (__hip_bfloat16*)(uni + 4352);    // [16][264]       8448 B -> 12800

    int bid = blockIdx.x;
    int b = bid & 7;                    // XCD-aware
    int rest = bid >> 3;
    int h = rest >> 2, wq = rest & 3;
    int w0 = wq * 16;
    int tid = threadIdx.x, lane = tid & 63, w = tid >> 6;
    int l15 = lane & 15, l4 = lane >> 4;
    int px = l15, t4 = l4;

    h2v* xpw = xp + w * 1344;
    h2v* wgw = wgt2 + w * 882;

    // ---- stage geometry: 616 uint2 pairs (8ccp x 7r x 11), 10 iters x 64 lanes ----
    int goff[10];
    unsigned short ldso[10];
#pragma unroll
    for (int e = 0; e < 10; ++e) {
        int i = lane + e * 64;
        bool ok = i < 616;
        int ii = ok ? i : 0;
        int ccp = ii / 77;
        int rem = ii - ccp * 77;
        int r = rem / 11, pr = rem - r * 11;
        goff[e] = ccp * 5040 + (h + r) * 72 + w0 + pr * 2;
        ldso[e] = (unsigned short)(ccp * 168 + r * 24 + pr * 2);
    }

    auto stageLoad = [&](int g, uint2* v) {
        const unsigned* xg = xpad + (size_t)(b * 64 + g * 8) * 5040;
#pragma unroll
        for (int e = 0; e < 10; ++e)
            v[e] = *(const uint2*)&xg[goff[e]];
    };
    // write through h2v (same alias class as involution reads -> order preserved)
    auto stageWrite = [&](uint2* v) {
#pragma unroll
        for (int e = 0; e < 10; ++e)
            if (e < 9 || lane < 40) {
                xpw[ldso[e]]     = __builtin_bit_cast(h2v, v[e].x);
                xpw[ldso[e] + 1] = __builtin_bit_cast(h2v, v[e].y);
            }
    };

    // ---- conv1 via MFMA: wave w computes n-tile w (16 out-channels) ----
    bf16x8 afr[4];
#pragma unroll
    for (int ks = 0; ks < 4; ++ks)
#pragma unroll
        for (int i = 0; i < 8; ++i) {
            int c = ks * 32 + l4 * 8 + i;
            afr[ks][i] = tobf(x[(((size_t)b * DIM + c) * Hs + h) * Ws + w0 + l15]);
        }
    {
        uint2 v[10];
        stageLoad(w * 4, v);               // overlap group-(4w) staging with conv1
        f32x4 acc1 = (f32x4){0.f, 0.f, 0.f, 0.f};
#pragma unroll
        for (int ks = 0; ks < 4; ++ks) {
            bf16x8 bf = *(const bf16x8*)&w1b[(w * 16 + l15) * DIM + ks * 32 + l4 * 8];
            acc1 = mfma16(afr[ks], bf, acc1);
        }
        int o = w * 16 + l15;
        float sc = bng[o] * rsqrtf(bnv[o] + 1e-5f);
        float sh = bnb[o] - bnm[o] * sc;
        float bv = b1v[o];
#pragma unroll
        for (int r = 0; r < 4; ++r) {
            float vv = (acc1[r] + bv) * sc + sh;
            tsh[(l4 * 4 + r) * 34 + o] = __float2bfloat16(fmaxf(vv, 0.f));
        }
        stageWrite(v);
    }
    __syncthreads();   // #1: tsh (both halves) + first stage ready
    bf16x8 a_t = *(const bf16x8*)&tsh[l15 * 34 + l4 * 8];

    unsigned ypk[8];    // word gl*2+pi: lo c=(w*4+gl)*16+t4*2+pi, hi +8
    float s = 0.f, ss = 0.f;

#pragma unroll 1
    for (int gl = 0; gl < 4; ++gl) {
        int g = w * 4 + gl;
        uint2 vN[10];
        if (gl < 3) stageLoad(g + 1, vN);   // issue early (T14)

        // conv2(g): 4 n-tiles
        {
            f32x4 ac[4];
#pragma unroll
            for (int nt = 0; nt < 4; ++nt) ac[nt] = (f32x4){0.f, 0.f, 0.f, 0.f};
#pragma unroll
            for (int nt = 0; nt < 4; ++nt) {
                bf16x8 bf = *(const bf16x8*)&w2b[(size_t)(g * 49 + nt * 16 + l15) * CMID + l4 * 8];
                ac[nt] = mfma16(a_t, bf, ac[nt]);
            }
#pragma unroll
            for (int nt = 0; nt < 4; ++nt) {
                int p = nt * 16 + l15;
                if (p < 49) {
                    float bias = b2v[g * 49 + p];
#pragma unroll
                    for (int r = 0; r < 4; ++r) {
                        _Float16 hf16 = (_Float16)(ac[nt][r] + bias);
                        wgw[p * 18 + l4 * 4 + r] = (h2v){hf16, hf16};
                    }
                }
            }
        }
        // same-wave in-order: wgw visible

        float a00 = 0.f, a01 = 0.f, a10 = 0.f, a11 = 0.f;
        {
            h2v wv[28];
#pragma unroll
            for (int p = 0; p < 28; ++p) wv[p] = wgw[p * 18 + px];
#pragma unroll
            for (int pi = 0; pi < 2; ++pi) {
                const h2v* xrow = xpw + (t4 * 2 + pi) * 168;
                float ax = 0.f, ay2 = 0.f;
#pragma unroll
                for (int r = 0; r < 4; ++r) {
                    h2v hacc = (h2v){(_Float16)0.f, (_Float16)0.f};
#pragma unroll
                    for (int j = 0; j < 7; ++j)
                        hacc = wv[r * 7 + j] * xrow[r * 24 + px + j] + hacc;
                    ax += (float)hacc.x;
                    ay2 += (float)hacc.y;
                }
                if (pi == 0) { a00 = ax; a01 = ay2; } else { a10 = ax; a11 = ay2; }
            }
        }
        {
            h2v wv[21];
#pragma unroll
            for (int p = 0; p < 21; ++p) wv[p] = wgw[(28 + p) * 18 + px];
#pragma unroll
            for (int pi = 0; pi < 2; ++pi) {
                const h2v* xrow = xpw + (t4 * 2 + pi) * 168;
                float ax = 0.f, ay2 = 0.f;
#pragma unroll
                for (int r = 0; r < 3; ++r) {
                    h2v hacc = (h2v){(_Float16)0.f, (_Float16)0.f};
#pragma unroll
                    for (int j = 0; j < 7; ++j)
                        hacc = wv[r * 7 + j] * xrow[(r + 4) * 24 + px + j] + hacc;
                    ax += (float)hacc.x;
                    ay2 += (float)hacc.y;
                }
                if (pi == 0) { a00 += ax; a01 += ay2; } else { a10 += ax; a11 += ay2; }
            }
        }
        ypk[gl * 2]     = su16(a00) | (su16(a01) << 16);
        ypk[gl * 2 + 1] = su16(a10) | (su16(a11) << 16);
        s += (a00 + a01) + (a10 + a11);
        ss = fmaf(a00, a00, fmaf(a01, a01, fmaf(a10, a10, fmaf(a11, a11, ss))));

        if (gl < 3) stageWrite(vN);         // write late (h2v stores: ordered after reads)
    }

    // ---- LayerNorm: intra-wave quad shfl + cross-wave LDS (dedicated psA/psB) ----
    s += __shfl_xor(s, 16);  s += __shfl_xor(s, 32);
    ss += __shfl_xor(ss, 16); ss += __shfl_xor(ss, 32);
    if (lane < 16) { psA[w * 16 + px] = s; psB[w * 16 + px] = ss; }
    __syncthreads();   // #2: both waves' partials + group loops done
    float sa = psA[px] + psA[16 + px];
    float sb = psB[px] + psB[16 + px];
    float mu = sa * (1.f / DIM);
    float var = sb * (1.f / DIM) - mu * mu;
    float rs = rsqrtf(var + 1e-6f);

    {
        unsigned wds[8];
#pragma unroll
        for (int gl = 0; gl < 4; ++gl)
#pragma unroll
            for (int pi = 0; pi < 2; ++pi) {
                unsigned wk = ypk[gl * 2 + pi];
                float lo = __uint_as_float(wk << 16);
                float hi = __uint_as_float(wk & 0xffff0000u);
                int c0 = (w * 4 + gl) * 16 + t4 * 2 + pi, c1 = c0 + 8;
                lo = (lo - mu) * rs * lng[c0] + lnb[c0];
                hi = (hi - mu) * rs * lng[c1] + lnb[c1];
                wds[gl * 2 + pi] = su16(lo) | (su16(hi) << 16);
            }
        __hip_bfloat16* dst = ylds + px * 136 + w * 64 + t4 * 16;
        uint4 v1 = {wds[0], wds[1], wds[2], wds[3]};
        uint4 v2 = {wds[4], wds[5], wds[6], wds[7]};
        *(uint4*)&dst[0] = v1;
        *(uint4*)&dst[8] = v2;
    }
    __syncthreads();   // #3: ylds full rows ready

    // ---- MLP GEMM1: wave w computes f-half w (n-tiles 8w..8w+7) ----
    bf16x8 ay[4];
#pragma unroll
    for (int ks = 0; ks < 4; ++ks)
        ay[ks] = *(const bf16x8*)&ylds[l15 * 136 + ks * 32 + l4 * 8];

    {
        f32x4 zac[8];
#pragma unroll
        for (int n = 0; n < 8; ++n) zac[n] = (f32x4){0.f, 0.f, 0.f, 0.f};
#pragma unroll
        for (int ks = 0; ks < 4; ++ks)
#pragma unroll
            for (int n = 0; n < 8; ++n) {
                int nt = w * 8 + n;
                bf16x8 bf = *(const bf16x8*)&mw1b[(nt * 16 + l15) * DIM + ks * 32 + l4 * 8];
                zac[n] = mfma16(ay[ks], bf, zac[n]);
            }
#pragma unroll
        for (int n = 0; n < 8; ++n) {
            int nt = w * 8 + n;
            float bv = mb1[nt * 16 + l15];
#pragma unroll
            for (int r = 0; r < 4; ++r) {
                float vv = gelu_t(zac[n][r] + bv);
                zsh[(l4 * 4 + r) * 264 + nt * 16 + l15] = __float2bfloat16(vv);
            }
        }
    }
    __syncthreads();   // #4: zsh full K ready

    // ---- MLP GEMM2: wave w computes c-half w (n-tiles 4w..4w+3) ----
    bf16x8 az[8];
#pragma unroll
    for (int ks = 0; ks < 8; ++ks)
        az[ks] = *(const bf16x8*)&zsh[l15 * 264 + ks * 32 + l4 * 8];

    f32x4 oac[4];
#pragma unroll
    for (int n = 0; n < 4; ++n) oac[n] = (f32x4){0.f, 0.f, 0.f, 0.f};
#pragma unroll
    for (int ks = 0; ks < 8; ++ks)
#pragma unroll
        for (int n = 0; n < 4; ++n) {
            int nt = w * 4 + n;
            bf16x8 bf = *(const bf16x8*)&mw2b[(nt * 16 + l15) * 256 + ks * 32 + l4 * 8];
            oac[n] = mfma16(az[ks], bf, oac[n]);
        }

    float4 xr[4];
#pragma unroll
    for (int n = 0; n < 4; ++n) {
        int c = (w * 4 + n) * 16 + l15;
        xr[n] = *(const float4*)&x[(((size_t)b * DIM + c) * Hs + h) * Ws + w0 + l4 * 4];
    }
#pragma unroll
    for (int n = 0; n < 4; ++n) {
        int c = (w * 4 + n) * 16 + l15;
        float bv = mb2[c];
        size_t gi = (((size_t)b * DIM + c) * Hs + h) * Ws + w0 + l4 * 4;
        float4 o;
        o.x = oac[n][0] + bv + xr[n].x;
        o.y = oac[n][1] + bv + xr[n].y;
        o.z = oac[n][2] + bv + xr[n].z;
        o.w = oac[n][3] + bv + xr[n].w;
        *(float4*)&out[gi] = o;
    }
}

extern "C" void kernel_launch(void* const* d_in, const int* in_sizes, int n_in,
                              void* d_out, int out_size, void* d_ws, size_t ws_size,
                              hipStream_t stream) {
    const float* x       = (const float*)d_in[0];
    const float* conv1_w = (const float*)d_in[1];
    const float* conv1_b = (const float*)d_in[2];
    const float* bn_g    = (const float*)d_in[3];
    const float* bn_b    = (const float*)d_in[4];
    const float* bn_mean = (const float*)d_in[5];
    const float* bn_var  = (const float*)d_in[6];
    const float* conv2_w = (const float*)d_in[7];
    const float* conv2_b = (const float*)d_in[8];
    const float* ln_g    = (const float*)d_in[9];
    const float* ln_b    = (const float*)d_in[10];
    const float* pw1_w   = (const float*)d_in[11];
    const float* pw1_b   = (const float*)d_in[12];
    const float* pw2_w   = (const float*)d_in[13];
    const float* pw2_b   = (const float*)d_in[14];
    float* out = (float*)d_out;

    char* ws = (char*)d_ws;
    __hip_bfloat16* w1b  = (__hip_bfloat16*)ws;                   // 8 KB
    __hip_bfloat16* w2b  = (__hip_bfloat16*)(ws + 8192);          // 26 KB
    __hip_bfloat16* mw1b = (__hip_bfloat16*)(ws + 34816);         // 64 KB (K-perm)
    __hip_bfloat16* mw2b = (__hip_bfloat16*)(ws + 100352);        // 64 KB
    unsigned* xpad       = (unsigned*)(ws + (1 << 20));           // 10.3 MB padded pairs

    hipLaunchKernelGGL(k0_cvt, dim3(2048), dim3(256), 0, stream,
                       conv1_w, conv2_w, pw1_w, pw2_w, x,
                       w1b, w2b, mw1b, mw2b, xpad);
    hipLaunchKernelGGL(k_all, dim3(Bn * Hs * 4), dim3(128), 0, stream,
                       x, xpad, w1b, conv1_b, bn_g, bn_b, bn_mean, bn_var,
                       w2b, conv2_b, ln_g, ln_b,
                       mw1b, pw1_b, mw2b, pw2_b, out);
}

// Round 20
// 67.167 us; speedup vs baseline: 1.2930x; 1.2930x over previous
//
#include <hip/hip_runtime.h>
#include <hip/hip_bf16.h>
#include <math.h>

#define Bn   8
#define DIM  128
#define Hs   64
#define Ws   64
#define GC   16
#define Gn   8
#define CMID 32
#define NW   392
#define NWP  416

typedef __bf16 bf16x8 __attribute__((ext_vector_type(8)));
typedef float  f32x4  __attribute__((ext_vector_type(4)));
typedef _Float16 h2v  __attribute__((ext_vector_type(2)));
typedef __fp16   fp16x2 __attribute__((ext_vector_type(2)));

__device__ __forceinline__ f32x4 mfma16(bf16x8 a, bf16x8 b, f32x4 c) {
    return __builtin_amdgcn_mfma_f32_16x16x32_bf16(a, b, c, 0, 0, 0);
}
__device__ __forceinline__ __bf16 tobf(float v) {
    __hip_bfloat16 h = __float2bfloat16(v);
    return *reinterpret_cast<__bf16*>(&h);
}
__device__ __forceinline__ unsigned su16(float f) {
    __hip_bfloat16 h = __float2bfloat16(f);
    return (unsigned)*reinterpret_cast<unsigned short*>(&h);
}
__device__ __forceinline__ unsigned pk2u(float a, float b) {
    fp16x2 p = __builtin_amdgcn_cvt_pkrtz(a, b);
    return __builtin_bit_cast(unsigned, p);
}
__device__ __forceinline__ h2v u2h(unsigned u) { return __builtin_bit_cast(h2v, u); }
__device__ __forceinline__ float gelu_t(float v) {
    float u = 0.7978845608f * v * fmaf(0.044715f, v * v, 1.0f);
    float t = __builtin_amdgcn_exp2f(fminf(u, 30.f) * 2.885390082f);
    return v * t * __builtin_amdgcn_rcpf(t + 1.0f);
}

// ---------------- K0: weights -> bf16 (+pw1 K-perm, R13 j-layout); x -> PADDED f16-pair image ----------------
// xpad[c8][70][72], c8=(b,g,ccp): prow=hh+3, pcol=wc+3, zero halo. pairs (c, c+8).
// k_all j layout: j = t4*32 + g*4 + pi*2 + sel -> c = g*16 + t4*2 + pi + 8*sel
__global__ __launch_bounds__(256) void k0_cvt(const float* __restrict__ w1,
        const float* __restrict__ w2,
        const float* __restrict__ pw1, const float* __restrict__ pw2,
        const float* __restrict__ x,
        __hip_bfloat16* __restrict__ w1b, __hip_bfloat16* __restrict__ w2b,
        __hip_bfloat16* __restrict__ mw1b, __hip_bfloat16* __restrict__ mw2b,
        unsigned* __restrict__ xpad) {
    int T = blockIdx.x * 256 + threadIdx.x;   // 524288 threads
    if (T < 32768) {
        int i = T;
        if (i < CMID * DIM) w1b[i] = __float2bfloat16(w1[i]);
        if (i < NWP * CMID)
            w2b[i] = (i < NW * CMID) ? __float2bfloat16(w2[i]) : __float2bfloat16(0.f);
        {
            int f = i >> 7, j = i & 127;
            int t4 = j >> 5, k = j & 31;
            int g = k >> 2, pi = (k >> 1) & 1, sel = k & 1;
            mw1b[i] = __float2bfloat16(pw1[f * 128 + g * 16 + t4 * 2 + pi + 8 * sel]);
        }
        mw2b[i] = __float2bfloat16(pw2[i]);
    }
#pragma unroll
    for (int e = 0; e < 5; ++e) {
        int idx = T + e * 524288;
        if (idx < 512 * 5040) {
            int c8 = idx / 5040;
            int rem = idx - c8 * 5040;
            int prow = rem / 72, pcol = rem - prow * 72;
            int hh = prow - 3, wc = pcol - 3;
            int bb = c8 >> 6, gg = (c8 >> 3) & 7, cc = c8 & 7;
            unsigned v = 0;
            if ((unsigned)hh < 64u && (unsigned)wc < 64u) {
                size_t src = ((size_t)(bb * DIM + gg * GC + cc)) * 4096 + hh * 64 + wc;
                v = pk2u(x[src], x[src + 8 * 4096]);
            }
            xpad[(size_t)c8 * 5040 + rem] = v;
        }
    }
}

// ---- K_ALL: 1 wave / 16-px tile; involution via global loads + DPP shifts; zero barriers ----
__global__ __launch_bounds__(64) void k_all(const float* __restrict__ x,
        const unsigned* __restrict__ xpad,
        const __hip_bfloat16* __restrict__ w1b, const float* __restrict__ b1v,
        const float* __restrict__ bng, const float* __restrict__ bnb,
        const float* __restrict__ bnm, const float* __restrict__ bnv,
        const __hip_bfloat16* __restrict__ w2b, const float* __restrict__ b2v,
        const float* __restrict__ lng, const float* __restrict__ lnb,
        const __hip_bfloat16* __restrict__ mw1b, const float* __restrict__ mb1,
        const __hip_bfloat16* __restrict__ mw2b, const float* __restrict__ mb2,
        float* __restrict__ out) {
    // all views DISJOINT (no union aliasing): 17216 B total
    __shared__ __align__(16) char uni[17216];
    __hip_bfloat16* tsh   = (__hip_bfloat16*)uni;             // [16][34]  1088 B
    h2v*            wgt2T = (h2v*)(uni + 1088);               // [16][52]  3328 B  (pixel-major!)
    __hip_bfloat16* ylds  = (__hip_bfloat16*)(uni + 4416);    // [16][136] 4352 B
    __hip_bfloat16* zsh   = (__hip_bfloat16*)(uni + 8768);    // [16][264] 8448 B

    int bid = blockIdx.x;
    int b = bid & 7;                    // XCD-aware: batch b -> XCD b (xpad slice L2-resident)
    int rest = bid >> 3;
    int h = rest >> 2, wq = rest & 3;
    int w0 = wq * 16;
    int lane = threadIdx.x;
    int l15 = lane & 15, l4 = lane >> 4;
    int px = l15, t4 = l4;

    // ---- conv1 via MFMA ----
    bf16x8 afr[4];
#pragma unroll
    for (int ks = 0; ks < 4; ++ks)
#pragma unroll
        for (int i = 0; i < 8; ++i) {
            int c = ks * 32 + l4 * 8 + i;
            afr[ks][i] = tobf(x[(((size_t)b * DIM + c) * Hs + h) * Ws + w0 + l15]);
        }
    f32x4 acc1[2];
    acc1[0] = (f32x4){0.f, 0.f, 0.f, 0.f};
    acc1[1] = (f32x4){0.f, 0.f, 0.f, 0.f};
#pragma unroll
    for (int nt = 0; nt < 2; ++nt)
#pragma unroll
        for (int ks = 0; ks < 4; ++ks) {
            bf16x8 bf = *(const bf16x8*)&w1b[(nt * 16 + l15) * DIM + ks * 32 + l4 * 8];
            acc1[nt] = mfma16(afr[ks], bf, acc1[nt]);
        }
#pragma unroll
    for (int nt = 0; nt < 2; ++nt) {
        int o = nt * 16 + l15;
        float sc = bng[o] * rsqrtf(bnv[o] + 1e-5f);
        float sh = bnb[o] - bnm[o] * sc;
        float bv = b1v[o];
#pragma unroll
        for (int r = 0; r < 4; ++r) {
            float v = (acc1[nt][r] + bv) * sc + sh;
            tsh[(l4 * 4 + r) * 34 + o] = __float2bfloat16(fmaxf(v, 0.f));
        }
    }
    // same wave: tsh in-order visible
    bf16x8 a_t = *(const bf16x8*)&tsh[l15 * 34 + l4 * 8];

    unsigned ypk[16];   // word g*2+pi: lo c=g*16+t4*2+pi, hi +8
    float s = 0.f, ss = 0.f;

#pragma unroll 1
    for (int g = 0; g < Gn; ++g) {
        // ---- batch-load window registers from xpad (L2-hit; coalesced per 16-lane row) ----
        unsigned Ax[14], Bx[14];
#pragma unroll
        for (int pi = 0; pi < 2; ++pi)
#pragma unroll
            for (int r = 0; r < 7; ++r) {
                const unsigned* rp = xpad + (size_t)(b * 64 + g * 8 + t4 * 2 + pi) * 5040
                                   + (h + r) * 72 + w0;
                Ax[pi * 7 + r] = rp[px];
                Bx[pi * 7 + r] = rp[px + 16];
            }

        // ---- conv2(g) via MFMA -> wgt2T[pixel][tap] ----
        {
            f32x4 ac[4];
#pragma unroll
            for (int nt = 0; nt < 4; ++nt) ac[nt] = (f32x4){0.f, 0.f, 0.f, 0.f};
#pragma unroll
            for (int nt = 0; nt < 4; ++nt) {
                bf16x8 bf = *(const bf16x8*)&w2b[(size_t)(g * 49 + nt * 16 + l15) * CMID + l4 * 8];
                ac[nt] = mfma16(a_t, bf, ac[nt]);
            }
#pragma unroll
            for (int nt = 0; nt < 4; ++nt) {
                int p = nt * 16 + l15;
                if (p < 49) {
                    float bias = b2v[g * 49 + p];
#pragma unroll
                    for (int r = 0; r < 4; ++r) {
                        _Float16 hf16 = (_Float16)(ac[nt][r] + bias);
                        wgt2T[(l4 * 4 + r) * 52 + p] = (h2v){hf16, hf16};
                    }
                }
            }
        }
        // same-wave in-order: wgt2T visible

        // ---- wv: 13 x b128 contiguous reads of row px ----
        h2v wv[52];
#pragma unroll
        for (int u = 0; u < 13; ++u) {
            uint4 t = *(const uint4*)&wgt2T[px * 52 + u * 4];
            wv[u * 4 + 0] = u2h(t.x);
            wv[u * 4 + 1] = u2h(t.y);
            wv[u * 4 + 2] = u2h(t.z);
            wv[u * 4 + 3] = u2h(t.w);
        }

        // ---- involution via DPP taps: A row_shl:J (lane i <- i+J), B row_shr:16-J (lane i <- i-(16-J)) ----
#define INV_TAP(J)                                                                          \
        {                                                                                   \
            unsigned ta = (unsigned)__builtin_amdgcn_update_dpp(                            \
                0, (int)A, 0x100 + J, 0xF, 0xF, false);                                     \
            unsigned tb = (unsigned)__builtin_amdgcn_update_dpp(                            \
                0, (int)B, 0x110 + (16 - J), 0xF, 0xF, false);                              \
            hacc = wv[r * 7 + J] * u2h(ta | tb) + hacc;                                     \
        }
        float acc[2][2];
#pragma unroll
        for (int pi = 0; pi < 2; ++pi) {
            float ax = 0.f, ay2 = 0.f;
#pragma unroll
            for (int r = 0; r < 7; ++r) {
                unsigned A = Ax[pi * 7 + r], B = Bx[pi * 7 + r];
                h2v hacc = wv[r * 7] * u2h(A);              // j = 0
                INV_TAP(1) INV_TAP(2) INV_TAP(3)
                INV_TAP(4) INV_TAP(5) INV_TAP(6)
                ax += (float)hacc.x;
                ay2 += (float)hacc.y;
            }
            acc[pi][0] = ax; acc[pi][1] = ay2;
        }
#undef INV_TAP
#pragma unroll
        for (int pi = 0; pi < 2; ++pi) {
            ypk[g * 2 + pi] = su16(acc[pi][0]) | (su16(acc[pi][1]) << 16);
            s += acc[pi][0] + acc[pi][1];
            ss = fmaf(acc[pi][0], acc[pi][0], fmaf(acc[pi][1], acc[pi][1], ss));
        }
    }

    // ---- LayerNorm: quad reduce over lanes {px, px+16, px+32, px+48} ----
    s += __shfl_xor(s, 16);  s += __shfl_xor(s, 32);
    ss += __shfl_xor(ss, 16); ss += __shfl_xor(ss, 32);
    float mu = s * (1.f / DIM);
    float var = ss * (1.f / DIM) - mu * mu;
    float rs = rsqrtf(var + 1e-6f);

    {
        unsigned wds[16];
#pragma unroll
        for (int g = 0; g < 8; ++g)
#pragma unroll
            for (int pi = 0; pi < 2; ++pi) {
                unsigned wk = ypk[g * 2 + pi];
                float lo = __uint_as_float(wk << 16);
                float hi = __uint_as_float(wk & 0xffff0000u);
                int c0 = g * 16 + t4 * 2 + pi, c1 = c0 + 8;
                lo = (lo - mu) * rs * lng[c0] + lnb[c0];
                hi = (hi - mu) * rs * lng[c1] + lnb[c1];
                wds[g * 2 + pi] = su16(lo) | (su16(hi) << 16);
            }
        __hip_bfloat16* dst = ylds + px * 136 + t4 * 32;
#pragma unroll
        for (int c4 = 0; c4 < 4; ++c4) {
            uint4 vv = {wds[c4 * 4 + 0], wds[c4 * 4 + 1], wds[c4 * 4 + 2], wds[c4 * 4 + 3]};
            *(uint4*)&dst[c4 * 8] = vv;
        }
    }
    // same wave: ylds in-order visible (disjoint region)

    // ---- MLP GEMM1 ----
    bf16x8 ay[4];
#pragma unroll
    for (int ks = 0; ks < 4; ++ks)
        ay[ks] = *(const bf16x8*)&ylds[l15 * 136 + ks * 32 + l4 * 8];

#pragma unroll
    for (int half = 0; half < 2; ++half) {
        f32x4 zac[8];
#pragma unroll
        for (int n = 0; n < 8; ++n) zac[n] = (f32x4){0.f, 0.f, 0.f, 0.f};
#pragma unroll
        for (int ks = 0; ks < 4; ++ks)
#pragma unroll
            for (int n = 0; n < 8; ++n) {
                int nt = half * 8 + n;
                bf16x8 bf = *(const bf16x8*)&mw1b[(nt * 16 + l15) * DIM + ks * 32 + l4 * 8];
                zac[n] = mfma16(ay[ks], bf, zac[n]);
            }
#pragma unroll
        for (int n = 0; n < 8; ++n) {
            int nt = half * 8 + n;
            float bv = mb1[nt * 16 + l15];
#pragma unroll
            for (int r = 0; r < 4; ++r) {
                float v = gelu_t(zac[n][r] + bv);
                zsh[(l4 * 4 + r) * 264 + nt * 16 + l15] = __float2bfloat16(v);
            }
        }
    }
    // same wave: zsh in-order visible

    bf16x8 az[8];
#pragma unroll
    for (int ks = 0; ks < 8; ++ks)
        az[ks] = *(const bf16x8*)&zsh[l15 * 264 + ks * 32 + l4 * 8];

    f32x4 oac[8];
#pragma unroll
    for (int n = 0; n < 8; ++n) oac[n] = (f32x4){0.f, 0.f, 0.f, 0.f};
#pragma unroll
    for (int ks = 0; ks < 8; ++ks)
#pragma unroll
        for (int n = 0; n < 8; ++n) {
            bf16x8 bf = *(const bf16x8*)&mw2b[(n * 16 + l15) * 256 + ks * 32 + l4 * 8];
            oac[n] = mfma16(az[ks], bf, oac[n]);
        }

    float4 xr[8];
#pragma unroll
    for (int n = 0; n < 8; ++n) {
        int c = n * 16 + l15;
        xr[n] = *(const float4*)&x[(((size_t)b * DIM + c) * Hs + h) * Ws + w0 + l4 * 4];
    }
#pragma unroll
    for (int n = 0; n < 8; ++n) {
        int c = n * 16 + l15;
        float bv = mb2[c];
        size_t gi = (((size_t)b * DIM + c) * Hs + h) * Ws + w0 + l4 * 4;
        float4 o;
        o.x = oac[n][0] + bv + xr[n].x;
        o.y = oac[n][1] + bv + xr[n].y;
        o.z = oac[n][2] + bv + xr[n].z;
        o.w = oac[n][3] + bv + xr[n].w;
        *(float4*)&out[gi] = o;
    }
}

extern "C" void kernel_launch(void* const* d_in, const int* in_sizes, int n_in,
                              void* d_out, int out_size, void* d_ws, size_t ws_size,
                              hipStream_t stream) {
    const float* x       = (const float*)d_in[0];
    const float* conv1_w = (const float*)d_in[1];
    const float* conv1_b = (const float*)d_in[2];
    const float* bn_g    = (const float*)d_in[3];
    const float* bn_b    = (const float*)d_in[4];
    const float* bn_mean = (const float*)d_in[5];
    const float* bn_var  = (const float*)d_in[6];
    const float* conv2_w = (const float*)d_in[7];
    const float* conv2_b = (const float*)d_in[8];
    const float* ln_g    = (const float*)d_in[9];
    const float* ln_b    = (const float*)d_in[10];
    const float* pw1_w   = (const float*)d_in[11];
    const float* pw1_b   = (const float*)d_in[12];
    const float* pw2_w   = (const float*)d_in[13];
    const float* pw2_b   = (const float*)d_in[14];
    float* out = (float*)d_out;

    char* ws = (char*)d_ws;
    __hip_bfloat16* w1b  = (__hip_bfloat16*)ws;                   // 8 KB
    __hip_bfloat16* w2b  = (__hip_bfloat16*)(ws + 8192);          // 26 KB
    __hip_bfloat16* mw1b = (__hip_bfloat16*)(ws + 34816);         // 64 KB (K-perm)
    __hip_bfloat16* mw2b = (__hip_bfloat16*)(ws + 100352);        // 64 KB
    unsigned* xpad       = (unsigned*)(ws + (1 << 20));           // 10.3 MB (+slack)

    hipLaunchKernelGGL(k0_cvt, dim3(2048), dim3(256), 0, stream,
                       conv1_w, conv2_w, pw1_w, pw2_w, x,
                       w1b, w2b, mw1b, mw2b, xpad);
    hipLaunchKernelGGL(k_all, dim3(Bn * Hs * 4), dim3(64), 0, stream,
                       x, xpad, w1b, conv1_b, bn_g, bn_b, bn_mean, bn_var,
                       w2b, conv2_b, ln_g, ln_b,
                       mw1b, pw1_b, mw2b, pw2_b, out);
}